// Round 16
// baseline (5179.815 us; speedup 1.0000x reference)
//
#include <hip/hip_runtime.h>
#include <hip/hip_bf16.h>
#include <cstddef>

// MatchLSTM round 16: R15 +
//  - match_b: 256 blocks x 2 rows (was 128 x 4) -> all CUs active in recurrence
//  - match_d: q-GEMV k-split over 912 threads + LDS reduce (was 304-thread serial)
// Cell GEMV / e-pass / PV keep R13's proven named-variable scheduling.
// V=50000, E=300, H=300, C=3, TP=128, TH=64, B=256
#define HDIM 300
#define EDIM 300
#define BATCH 256
#define TPREM 128
#define THYP 64
#define KTT 32

typedef unsigned short us8 __attribute__((ext_vector_type(8)));

__device__ __forceinline__ float fast_sigm(float x) {
    return 1.f / (1.f + __expf(-x));
}
__device__ __forceinline__ float fast_tanh(float x) {
    float e = __expf(2.f * x);
    return 1.f - 2.f / (e + 1.f);
}
__device__ __forceinline__ unsigned short f2bf(float f) {
    __hip_bfloat16 h = __float2bfloat16(f);
    return *reinterpret_cast<unsigned short*>(&h);
}
__device__ __forceinline__ float bf2f(unsigned short u) {
    return __uint_as_float((unsigned)u << 16);
}

struct Params {
    const int* premise; const int* hypothesis;
    const float* w2v; const float* w_e;
    const float* W_s; const float* W_t; const float* W_m;
    const float* fc_w; const float* fc_b;
    const float* pWih; const float* pWhh; const float* pbih; const float* pbhh;
    const float* hWih; const float* hWhh; const float* hbih; const float* hbhh;
    const float* mWih; const float* mbih; const float* mbhh;
    float* h_t_all;          // [TH][B][H] fp32
    unsigned short* hsT;     // [B][TP][H] bf16
    unsigned short* wshsT;   // [B][TP][H] bf16
    unsigned short* wthtB;   // [TH][B][H] bf16
    unsigned short* Xp;      // [TP][64][1200][4] bf16 (bias folded)
    unsigned short* Xh;      // [TH][64][1200][4] bf16
    unsigned short* WhhW_p;  // [38 kg][1536 c][8] bf16
    unsigned short* WhhW_h;
    unsigned short* WmW3;    // [75 kg][1024 c][8] bf16 (mWih i,g,o cols)
    unsigned short* WmTw;    // [38 kg][304 c][8] bf16 (W_m^T)
    float* out;
};

// ===========================================================================
// k_init: build wide transposed bf16 weight buffers. (R13 layouts)
// ===========================================================================
__global__ void k_init(Params p) {
    const int stride = gridDim.x * 256;
    const int i0 = blockIdx.x * 256 + threadIdx.x;
    for (int i = i0; i < 38 * 1536 * 8; i += stride) {
        int kg = i / (1536 * 8);
        int rem = i - kg * (1536 * 8);
        int c = rem >> 3, j = rem & 7;
        int k = 8 * kg + j;
        float vp = 0.f, vh = 0.f;
        if (c < 1200 && k < 300) {
            vp = p.pWhh[(size_t)c * 300 + k];
            vh = p.hWhh[(size_t)c * 300 + k];
        }
        p.WhhW_p[i] = f2bf(vp);
        p.WhhW_h[i] = f2bf(vh);
    }
    for (int i = i0; i < 75 * 1024 * 8; i += stride) {
        int kg = i / (1024 * 8);
        int rem = i - kg * (1024 * 8);
        int c = rem >> 3, j = rem & 7;
        int k = 8 * kg + j;
        float v = 0.f;
        if (c < 900 && k < 600) {
            int row = c + (c < 300 ? 0 : 300);
            v = p.mWih[(size_t)row * 600 + k];
        }
        p.WmW3[i] = f2bf(v);
    }
    for (int i = i0; i < 38 * 304 * 8; i += stride) {
        int kg = i / (304 * 8);
        int rem = i - kg * (304 * 8);
        int c = rem >> 3, j = rem & 7;
        int k = 8 * kg + j;
        p.WmTw[i] = f2bf((c < 300 && k < 300) ? p.W_m[(size_t)c * 300 + k] : 0.f);
    }
}

// ===========================================================================
// k_xproj: X = emb(tok) @ Wih^T + bih + bhh, bf16 [t][g][c][4].
// 128x64 tiles. Grid: (256 prem + 128 hyp) x 19.
// ===========================================================================
__global__ __launch_bounds__(256, 2) void k_xproj(Params p) {
    __shared__ __align__(16) float As[16][136];
    __shared__ __align__(16) float Bs[16][68];
    __shared__ int toks[128];

    const int bid = blockIdx.x;
    const int mt = bid / 19, nt = bid % 19;
    const bool isP = mt < 256;
    const int m0 = (isP ? mt : mt - 256) * 128;
    const int n0 = nt * 64;
    const int* tk = isP ? p.premise : p.hypothesis;
    const float* W = isP ? p.pWih : p.hWih;
    const float* b1 = isP ? p.pbih : p.hbih;
    const float* b2 = isP ? p.pbhh : p.hbhh;
    unsigned short* X = isP ? p.Xp : p.Xh;
    const int tid = threadIdx.x;

    if (tid < 128) toks[tid] = tk[m0 + tid];
    __syncthreads();

    const int tm = tid & 15, tn = tid >> 4;
    float acc[8][4] = {};
    for (int k0 = 0; k0 < 300; k0 += 16) {
        for (int i = tid; i < 2048; i += 256) {
            int kk = i & 15, ml = i >> 4;
            int k = k0 + kk;
            As[kk][ml] = (k < 300)
                ? p.w2v[(size_t)toks[ml] * 300 + k] : 0.f;
        }
        for (int i = tid; i < 1024; i += 256) {
            int kk = i & 15, nl = i >> 4;
            int c = n0 + nl, k = k0 + kk;
            Bs[kk][nl] = (c < 1200 && k < 300)
                ? W[(size_t)c * 300 + k] : 0.f;
        }
        __syncthreads();
        #pragma unroll
        for (int kk = 0; kk < 16; ++kk) {
            float a[8], w[4];
            #pragma unroll
            for (int i = 0; i < 8; ++i) a[i] = As[kk][tm * 8 + i];
            #pragma unroll
            for (int j = 0; j < 4; ++j) w[j] = Bs[kk][tn * 4 + j];
            #pragma unroll
            for (int i = 0; i < 8; ++i)
                #pragma unroll
                for (int j = 0; j < 4; ++j)
                    acc[i][j] = fmaf(a[i], w[j], acc[i][j]);
        }
        __syncthreads();
    }
    #pragma unroll
    for (int i = 0; i < 8; ++i) {
        int rr = m0 + tm * 8 + i;
        int t = rr >> 8, b = rr & 255;
        int g = b >> 2, r = b & 3;
        size_t base = (size_t)(t * 64 + g) * 1200;
        #pragma unroll
        for (int j = 0; j < 4; ++j) {
            int c = n0 + tn * 4 + j;
            if (c < 1200)
                X[(base + c) * 4 + r] = f2bf(acc[i][j] + b1[c] + b2[c]);
        }
    }
}

// ===========================================================================
// match_b: recurrences. Block = 2 rows, 256 blocks x 512 thr (ALL CUs).
// kg loop batched 2-deep with NAMED us8 variables (R13-proven scheduling).
// ===========================================================================
__global__ __launch_bounds__(512, 2) void match_b(Params p) {
    __shared__ __align__(16) float2 A[304];    // h[t-1], 2 rows per float2
    __shared__ __align__(16) float2 G[1536];

    const int blk = blockIdx.x;
    const int tid = threadIdx.x;
    const bool isP = blk < 128;
    const int g = isP ? blk : blk - 128;
    const int b0 = g * 2;
    const int TS = isP ? TPREM : THYP;
    const unsigned short* WhhW = isP ? p.WhhW_p : p.WhhW_h;
    const unsigned short* Xbuf = isP ? p.Xp : p.Xh;
    const int g4 = b0 >> 2;          // 4-row group in X layout
    const int r0 = b0 & 3;           // 0 or 2

    if (tid < 304) A[tid] = {0, 0};
    float2 creg = {0, 0};
    __syncthreads();

    for (int t = 0; t < TS; ++t) {
        float2 ac0 = {0,0}, ac1 = {0,0}, ac2 = {0,0};
        {
            const unsigned short* w0 = WhhW + (size_t)tid * 8;
            const unsigned short* w1 = WhhW + (size_t)(tid + 512) * 8;
            const unsigned short* w2 = WhhW + (size_t)(tid + 1024) * 8;
            for (int kg = 0; kg < 38; kg += 2) {
                const size_t offA = (size_t)kg * (1536 * 8);
                const size_t offB = (size_t)(kg + 1) * (1536 * 8);
                us8 u0a = *reinterpret_cast<const us8*>(w0 + offA);
                us8 u1a = *reinterpret_cast<const us8*>(w1 + offA);
                us8 u2a = *reinterpret_cast<const us8*>(w2 + offA);
                us8 u0b = *reinterpret_cast<const us8*>(w0 + offB);
                us8 u1b = *reinterpret_cast<const us8*>(w1 + offB);
                us8 u2b = *reinterpret_cast<const us8*>(w2 + offB);
                #pragma unroll
                for (int j = 0; j < 8; ++j) {
                    float2 a = A[8 * kg + j];
                    float f0 = bf2f(u0a[j]), f1 = bf2f(u1a[j]), f2 = bf2f(u2a[j]);
                    ac0.x = fmaf(a.x, f0, ac0.x); ac0.y = fmaf(a.y, f0, ac0.y);
                    ac1.x = fmaf(a.x, f1, ac1.x); ac1.y = fmaf(a.y, f1, ac1.y);
                    ac2.x = fmaf(a.x, f2, ac2.x); ac2.y = fmaf(a.y, f2, ac2.y);
                }
                #pragma unroll
                for (int j = 0; j < 8; ++j) {
                    float2 a = A[8 * (kg + 1) + j];
                    float f0 = bf2f(u0b[j]), f1 = bf2f(u1b[j]), f2 = bf2f(u2b[j]);
                    ac0.x = fmaf(a.x, f0, ac0.x); ac0.y = fmaf(a.y, f0, ac0.y);
                    ac1.x = fmaf(a.x, f1, ac1.x); ac1.y = fmaf(a.y, f1, ac1.y);
                    ac2.x = fmaf(a.x, f2, ac2.x); ac2.y = fmaf(a.y, f2, ac2.y);
                }
            }
        }
        G[tid] = ac0;
        G[tid + 512] = ac1;
        G[tid + 1024] = ac2;
        __syncthreads();

        if (tid < 300) {
            const unsigned short* xb = Xbuf + (size_t)(t * 64 + g4) * 1200 * 4 + r0;
            ushort2 xi = *reinterpret_cast<const ushort2*>(xb + (size_t)tid * 4);
            ushort2 xf = *reinterpret_cast<const ushort2*>(xb + (size_t)(tid + 300) * 4);
            ushort2 xg = *reinterpret_cast<const ushort2*>(xb + (size_t)(tid + 600) * 4);
            ushort2 xo = *reinterpret_cast<const ushort2*>(xb + (size_t)(tid + 900) * 4);
            float2 g_i = G[tid], g_f = G[300 + tid];
            float2 g_g = G[600 + tid], g_o = G[900 + tid];
            float2 h2;
            {
                float gi = fast_sigm(g_i.x + bf2f(xi.x));
                float gf = fast_sigm(g_f.x + bf2f(xf.x));
                float gg = fast_tanh(g_g.x + bf2f(xg.x));
                float go = fast_sigm(g_o.x + bf2f(xo.x));
                creg.x = gf * creg.x + gi * gg; h2.x = go * fast_tanh(creg.x);
            }
            {
                float gi = fast_sigm(g_i.y + bf2f(xi.y));
                float gf = fast_sigm(g_f.y + bf2f(xf.y));
                float gg = fast_tanh(g_g.y + bf2f(xg.y));
                float go = fast_sigm(g_o.y + bf2f(xo.y));
                creg.y = gf * creg.y + gi * gg; h2.y = go * fast_tanh(creg.y);
            }
            A[tid] = h2;
            if (isP) {
                p.hsT[((size_t)(b0 + 0) * TPREM + t) * HDIM + tid] = f2bf(h2.x);
                p.hsT[((size_t)(b0 + 1) * TPREM + t) * HDIM + tid] = f2bf(h2.y);
            } else {
                const size_t rb = (size_t)(t * BATCH + b0);
                p.h_t_all[(rb + 0) * HDIM + tid] = h2.x;
                p.h_t_all[(rb + 1) * HDIM + tid] = h2.y;
            }
        }
        __syncthreads();
    }
}

// ===========================================================================
// k_proj: wshsT (premise, jobs 0..1023) and wthtB (hyp, 1024..1535).
// ===========================================================================
__global__ __launch_bounds__(256, 2) void k_proj(Params p) {
    __shared__ __align__(16) float hA[320][34];
    __shared__ __align__(16) float Bs[KTT][68];

    const int jb = blockIdx.x;
    const int tid = threadIdx.x;
    const int pb = tid & 15, hl = tid >> 4;
    const bool isP = jb < 1024;
    const int rt = isP ? jb : jb - 1024;
    const float* Wp = isP ? p.W_s : p.W_t;
    const int fb_c = tid >> 2, fb_k0 = (tid & 3) * 8;

    for (int i2 = tid; i2 < 32 * HDIM; i2 += 256) {
        int r = i2 / HDIM, k = i2 - r * HDIM;
        hA[k][r] = isP
            ? bf2f(p.hsT[(size_t)(rt * 32 + r) * HDIM + k])
            : p.h_t_all[(size_t)(rt * 32 + r) * HDIM + k];
    }
    for (int i2 = tid; i2 < 20 * 34; i2 += 256)
        hA[300 + i2 / 34][i2 % 34] = 0.f;
    __syncthreads();

    unsigned short* dst = isP ? p.wshsT : p.wthtB;

    for (int n0 = 0; n0 < HDIM; n0 += 64) {
        const int wrow = n0 + fb_c;
        const bool wvalid = wrow < HDIM;
        float acc[2][4] = {};
        for (int kc = 0; kc < HDIM; kc += KTT) {
            #pragma unroll
            for (int u = 0; u < 8; ++u) {
                int kk = fb_k0 + u, k = kc + kk;
                Bs[kk][fb_c] = (wvalid && k < HDIM)
                    ? Wp[(size_t)wrow * HDIM + k] : 0.f;
            }
            __syncthreads();
            #pragma unroll
            for (int kk = 0; kk < KTT; ++kk) {
                float2 av = *(const float2*)&hA[kc + kk][pb * 2];
                float4 wv = *(const float4*)&Bs[kk][hl * 4];
                acc[0][0] = fmaf(av.x, wv.x, acc[0][0]);
                acc[0][1] = fmaf(av.x, wv.y, acc[0][1]);
                acc[0][2] = fmaf(av.x, wv.z, acc[0][2]);
                acc[0][3] = fmaf(av.x, wv.w, acc[0][3]);
                acc[1][0] = fmaf(av.y, wv.x, acc[1][0]);
                acc[1][1] = fmaf(av.y, wv.y, acc[1][1]);
                acc[1][2] = fmaf(av.y, wv.z, acc[1][2]);
                acc[1][3] = fmaf(av.y, wv.w, acc[1][3]);
            }
            __syncthreads();
        }
        const int col = n0 + hl * 4;
        if (col < HDIM) {
            #pragma unroll
            for (int u = 0; u < 2; ++u) {
                size_t rr = (size_t)(rt * 32 + pb * 2 + u);
                ushort4 v4;
                v4.x = f2bf(acc[u][0]); v4.y = f2bf(acc[u][1]);
                v4.z = f2bf(acc[u][2]); v4.w = f2bf(acc[u][3]);
                *reinterpret_cast<ushort4*>(&dst[rr * HDIM + col]) = v4;
            }
        }
        __syncthreads();
    }
}

// ===========================================================================
// match_d: 256 blocks x 1024 thr, ONE row per block. (R13 core)
// q-GEMV k-split over 912 threads + LDS reduce; cell GEMV 5-deep named.
// ===========================================================================
__global__ __launch_bounds__(1024, 1) void match_d(Params p) {
    __shared__ __align__(16) float hm[304];
    __shared__ __align__(16) float q[304];
    __shared__ __align__(16) float we[304];
    __shared__ float alpha[TPREM];
    __shared__ __align__(16) float A6[608];
    __shared__ float G[1024];
    __shared__ __align__(16) float pvp[16][304];
    __shared__ __align__(16) float qp[3][304];

    const int b = blockIdx.x;
    const int tid = threadIdx.x;
    const int lane = tid & 63;
    const int wv = tid >> 6;          // 0..15
    const unsigned short* wsb = p.wshsT + (size_t)b * TPREM * HDIM;
    const unsigned short* hsb = p.hsT + (size_t)b * TPREM * HDIM;

    // q-split mapping: threads 0..911 -> (slice qs, col qc)
    const int qs = tid / 304;         // 0..3 (only <3 used)
    const int qc = tid - qs * 304;
    const int kg0 = (qs == 0) ? 0 : (qs == 1) ? 13 : 26;
    const int kg1 = (qs == 0) ? 13 : (qs == 1) ? 26 : 38;

    float bi0 = 0.f, bi2 = 0.f, bi3 = 0.f;
    if (tid < 304) { hm[tid] = 0.f; we[tid] = 0.f; q[tid] = 0.f; }
    if (tid >= 600 && tid < 608) A6[tid] = 0.f;
    if (tid < 300) {
        we[tid] = p.w_e[tid];
        bi0 = p.mbih[tid] + p.mbhh[tid];
        bi2 = p.mbih[600 + tid] + p.mbhh[600 + tid];
        bi3 = p.mbih[900 + tid] + p.mbhh[900 + tid];
    }
    __syncthreads();

    for (int k = 0; k < THYP; ++k) {
        // q = W_m @ h_m + wt_ht : 3-way k-split over 912 threads
        if (tid < 912) {
            float acc = 0.f;
            const unsigned short* w0 = p.WmTw + (size_t)qc * 8;
            for (int kg = kg0; kg < kg1; ++kg) {
                us8 ua = *reinterpret_cast<const us8*>(w0 + (size_t)kg * (304 * 8));
                #pragma unroll
                for (int j = 0; j < 8; ++j)
                    acc = fmaf(hm[8 * kg + j], bf2f(ua[j]), acc);
            }
            qp[qs][qc] = acc;
        }
        __syncthreads();
        if (tid < 300)
            q[tid] = qp[0][tid] + qp[1][tid] + qp[2][tid]
                   + bf2f(p.wthtB[((size_t)k * BATCH + b) * HDIM + tid]);
        __syncthreads();

        // e-pass (16 waves)
        for (int t = wv; t < TPREM; t += 16) {
            const unsigned short* row = wsb + (size_t)t * HDIM;
            ushort4 v4 = *reinterpret_cast<const ushort4*>(&row[4 * lane]);
            float4 q4 = *reinterpret_cast<const float4*>(&q[4 * lane]);
            float4 we4 = *reinterpret_cast<const float4*>(&we[4 * lane]);
            float pp;
            pp  = we4.x * fast_tanh(bf2f(v4.x) + q4.x);
            pp += we4.y * fast_tanh(bf2f(v4.y) + q4.y);
            pp += we4.z * fast_tanh(bf2f(v4.z) + q4.z);
            pp += we4.w * fast_tanh(bf2f(v4.w) + q4.w);
            if (lane < 44) {
                int h = 256 + lane;
                pp += we[h] * fast_tanh(bf2f(row[h]) + q[h]);
            }
            #pragma unroll
            for (int off = 32; off; off >>= 1) pp += __shfl_xor(pp, off, 64);
            if (lane == 0) alpha[t] = pp;
        }
        __syncthreads();

        // softmax over 128 (wave 0)
        if (wv == 0) {
            float e0 = alpha[lane], e1 = alpha[64 + lane];
            float m = fmaxf(e0, e1);
            #pragma unroll
            for (int off = 32; off; off >>= 1) m = fmaxf(m, __shfl_xor(m, off, 64));
            e0 = __expf(e0 - m); e1 = __expf(e1 - m);
            float s = e0 + e1;
            #pragma unroll
            for (int off = 32; off; off >>= 1) s += __shfl_xor(s, off, 64);
            float inv = 1.f / s;
            alpha[lane] = e0 * inv;
            alpha[64 + lane] = e1 * inv;
        }
        __syncthreads();

        // PV (16 waves)
        {
            float4 acc = {0, 0, 0, 0};
            float at = 0.f;
            for (int t = wv; t < TPREM; t += 16) {
                float wgt = alpha[t];
                const unsigned short* row = hsb + (size_t)t * HDIM;
                ushort4 v4 = *reinterpret_cast<const ushort4*>(&row[4 * lane]);
                acc.x = fmaf(wgt, bf2f(v4.x), acc.x);
                acc.y = fmaf(wgt, bf2f(v4.y), acc.y);
                acc.z = fmaf(wgt, bf2f(v4.z), acc.z);
                acc.w = fmaf(wgt, bf2f(v4.w), acc.w);
                if (lane < 44) at = fmaf(wgt, bf2f(row[256 + lane]), at);
            }
            *reinterpret_cast<float4*>(&pvp[wv][4 * lane]) = acc;
            if (lane < 44) pvp[wv][256 + lane] = at;
        }
        __syncthreads();

        // A6 = [ab | h_t]
        if (tid < 300) {
            float s = 0.f;
            #pragma unroll
            for (int w16 = 0; w16 < 16; ++w16) s += pvp[w16][tid];
            A6[tid] = s;
            A6[300 + tid] = p.h_t_all[((size_t)k * BATCH + b) * HDIM + tid];
        }
        __syncthreads();

        // cell GEMM: ONE col per thread; loads 5-deep NAMED (75 = 15*5, R13)
        {
            float acc0 = 0.f;
            const unsigned short* w0 = p.WmW3 + (size_t)tid * 8;
            for (int kb = 0; kb < 75; kb += 5) {
                us8 u0 = *reinterpret_cast<const us8*>(w0 + (size_t)(kb + 0) * (1024 * 8));
                us8 u1 = *reinterpret_cast<const us8*>(w0 + (size_t)(kb + 1) * (1024 * 8));
                us8 u2 = *reinterpret_cast<const us8*>(w0 + (size_t)(kb + 2) * (1024 * 8));
                us8 u3 = *reinterpret_cast<const us8*>(w0 + (size_t)(kb + 3) * (1024 * 8));
                us8 u4 = *reinterpret_cast<const us8*>(w0 + (size_t)(kb + 4) * (1024 * 8));
                #pragma unroll
                for (int j = 0; j < 8; ++j)
                    acc0 = fmaf(A6[8 * (kb + 0) + j], bf2f(u0[j]), acc0);
                #pragma unroll
                for (int j = 0; j < 8; ++j)
                    acc0 = fmaf(A6[8 * (kb + 1) + j], bf2f(u1[j]), acc0);
                #pragma unroll
                for (int j = 0; j < 8; ++j)
                    acc0 = fmaf(A6[8 * (kb + 2) + j], bf2f(u2[j]), acc0);
                #pragma unroll
                for (int j = 0; j < 8; ++j)
                    acc0 = fmaf(A6[8 * (kb + 3) + j], bf2f(u3[j]), acc0);
                #pragma unroll
                for (int j = 0; j < 8; ++j)
                    acc0 = fmaf(A6[8 * (kb + 4) + j], bf2f(u4[j]), acc0);
            }
            G[tid] = acc0;
        }
        __syncthreads();

        if (tid < 300) {
            float gi = fast_sigm(G[tid] + bi0);
            float gg = fast_tanh(G[300 + tid] + bi2);
            float go = fast_sigm(G[600 + tid] + bi3);
            hm[tid] = go * fast_tanh(gi * gg);
        }
        __syncthreads();
    }

    // FC (wave 0)
    if (wv == 0) {
        float p0 = 0.f, p1 = 0.f, p2 = 0.f;
        #pragma unroll
        for (int i = 0; i < 5; ++i) {
            int h = lane + 64 * i;
            if (h < HDIM) {
                float v = hm[h];
                p0 = fmaf(v, p.fc_w[h], p0);
                p1 = fmaf(v, p.fc_w[HDIM + h], p1);
                p2 = fmaf(v, p.fc_w[2 * HDIM + h], p2);
            }
        }
        #pragma unroll
        for (int off = 32; off; off >>= 1) {
            p0 += __shfl_xor(p0, off, 64);
            p1 += __shfl_xor(p1, off, 64);
            p2 += __shfl_xor(p2, off, 64);
        }
        if (lane == 0) {
            p.out[b * 3 + 0] = p0 + p.fc_b[0];
            p.out[b * 3 + 1] = p1 + p.fc_b[1];
            p.out[b * 3 + 2] = p2 + p.fc_b[2];
        }
    }
}

// ===========================================================================
// Fallback path: round-1 multi-kernel implementation (proven correct).
// ===========================================================================
__global__ void k_lstm_gates(
    const int* __restrict__ tok, const float* __restrict__ w2v,
    const float* __restrict__ A0, int K0,
    const float* __restrict__ A1, int K1,
    const float* __restrict__ W0, int ld0,
    const float* __restrict__ W1, int ld1,
    const float* __restrict__ bih, const float* __restrict__ bhh,
    const float* __restrict__ c_in, float* __restrict__ c_out,
    float* __restrict__ h_out)
{
    constexpr int KT = 32;
    __shared__ __align__(16) float As[KT][34];
    __shared__ __align__(16) float Bs[KT][68];

    const int tid = threadIdx.x;
    const int b0 = blockIdx.x * 32;
    const int hh0 = blockIdx.y * 16;
    const int K = K0 + K1;
    const int pb = tid & 15;
    const int hl = tid >> 4;
    const int fa_b = tid >> 3;
    const int fa_k0 = (tid & 7) * 4;
    const int fb_c = tid >> 2;
    const int fb_k0 = (tid & 3) * 8;
    const int fb_hh = hh0 + (fb_c >> 2);
    const int fb_g = fb_c & 3;
    const int fb_row = fb_g * HDIM + fb_hh;
    const bool fb_valid = fb_hh < HDIM;
    const int ga = b0 + fa_b;
    const int tok_b = tok ? tok[ga] : 0;

    float acc[2][4] = {{0.f,0.f,0.f,0.f},{0.f,0.f,0.f,0.f}};

    for (int k0 = 0; k0 < K; k0 += KT) {
        #pragma unroll
        for (int u = 0; u < 4; ++u) {
            int kk = fa_k0 + u;
            int k = k0 + kk;
            float v = 0.f;
            if (k < K0)      v = tok ? w2v[(size_t)tok_b * K0 + k]
                                     : A0[(size_t)ga * K0 + k];
            else if (k < K)  v = A1[(size_t)ga * K1 + (k - K0)];
            As[kk][fa_b] = v;
        }
        #pragma unroll
        for (int u = 0; u < 8; ++u) {
            int kk = fb_k0 + u;
            int k = k0 + kk;
            float v = 0.f;
            if (fb_valid) {
                if (k < K0)     v = W0[(size_t)fb_row * ld0 + k];
                else if (k < K) v = W1[(size_t)fb_row * ld1 + (k - K0)];
            }
            Bs[kk][fb_c] = v;
        }
        __syncthreads();
        #pragma unroll
        for (int kk = 0; kk < KT; ++kk) {
            float2 av = *(const float2*)&As[kk][pb * 2];
            float4 wv = *(const float4*)&Bs[kk][hl * 4];
            acc[0][0] = fmaf(av.x, wv.x, acc[0][0]);
            acc[0][1] = fmaf(av.x, wv.y, acc[0][1]);
            acc[0][2] = fmaf(av.x, wv.z, acc[0][2]);
            acc[0][3] = fmaf(av.x, wv.w, acc[0][3]);
            acc[1][0] = fmaf(av.y, wv.x, acc[1][0]);
            acc[1][1] = fmaf(av.y, wv.y, acc[1][1]);
            acc[1][2] = fmaf(av.y, wv.z, acc[1][2]);
            acc[1][3] = fmaf(av.y, wv.w, acc[1][3]);
        }
        __syncthreads();
    }

    const int hh = hh0 + hl;
    if (hh < HDIM) {
        float bi = bih[hh] + bhh[hh];
        float bf = bih[HDIM + hh] + bhh[HDIM + hh];
        float bg = bih[2 * HDIM + hh] + bhh[2 * HDIM + hh];
        float bo = bih[3 * HDIM + hh] + bhh[3 * HDIM + hh];
        #pragma unroll
        for (int u = 0; u < 2; ++u) {
            int b = b0 + pb * 2 + u;
            float gi = fast_sigm(acc[u][0] + bi);
            float gf = fast_sigm(acc[u][1] + bf);
            float gg = fast_tanh(acc[u][2] + bg);
            float go = fast_sigm(acc[u][3] + bo);
            float c = gf * c_in[(size_t)b * HDIM + hh] + gi * gg;
            c_out[(size_t)b * HDIM + hh] = c;
            h_out[(size_t)b * HDIM + hh] = go * fast_tanh(c);
        }
    }
}

template<int BM, int BN, int TM, int TN, int KT>
__global__ void k_gemm_tn(
    const float* __restrict__ A0, int K0,
    const float* __restrict__ A1, int K1,
    const float* __restrict__ B0, int ldb0,
    const float* __restrict__ B1, int ldb1,
    float* __restrict__ C, int M, int N)
{
    __shared__ __align__(16) float As[KT][BM + 4];
    __shared__ __align__(16) float Bs[KT][BN + 4];
    const int tid = threadIdx.x;
    const int m0 = blockIdx.x * BM;
    const int n0 = blockIdx.y * BN;
    const int K = K0 + K1;
    constexpr int TPM = BM / TM;
    const int tm = tid % TPM;
    const int tn = tid / TPM;

    float acc[TM][TN];
    #pragma unroll
    for (int i = 0; i < TM; ++i)
        #pragma unroll
        for (int j = 0; j < TN; ++j) acc[i][j] = 0.f;

    for (int k0 = 0; k0 < K; k0 += KT) {
        for (int i = tid; i < KT * BM; i += 256) {
            int kk = i % KT, ml = i / KT;
            int m = m0 + ml, k = k0 + kk;
            float v = 0.f;
            if (m < M) {
                if (k < K0)     v = A0[(size_t)m * K0 + k];
                else if (k < K) v = A1[(size_t)m * K1 + (k - K0)];
            }
            As[kk][ml] = v;
        }
        for (int i = tid; i < KT * BN; i += 256) {
            int kk = i % KT, nl = i / KT;
            int n = n0 + nl, k = k0 + kk;
            float v = 0.f;
            if (n < N) {
                if (k < K0)     v = B0[(size_t)n * ldb0 + k];
                else if (k < K) v = B1[(size_t)n * ldb1 + (k - K0)];
            }
            Bs[kk][nl] = v;
        }
        __syncthreads();
        #pragma unroll
        for (int kk = 0; kk < KT; ++kk) {
            float a[TM], w[TN];
            #pragma unroll
            for (int i = 0; i < TM; ++i) a[i] = As[kk][tm * TM + i];
            #pragma unroll
            for (int j = 0; j < TN; ++j) w[j] = Bs[kk][tn * TN + j];
            #pragma unroll
            for (int i = 0; i < TM; ++i)
                #pragma unroll
                for (int j = 0; j < TN; ++j)
                    acc[i][j] = fmaf(a[i], w[j], acc[i][j]);
        }
        __syncthreads();
    }
    #pragma unroll
    for (int i = 0; i < TM; ++i) {
        int m = m0 + tm * TM + i;
        if (m >= M) continue;
        #pragma unroll
        for (int j = 0; j < TN; ++j) {
            int n = n0 + tn * TN + j;
            if (n < N) C[(size_t)m * N + n] = acc[i][j];
        }
    }
}

__global__ void k_attn(const float* __restrict__ ws_hs,
                       const float* __restrict__ h_s,
                       const float* __restrict__ q,
                       const float* __restrict__ w_e,
                       float* __restrict__ a_out)
{
    const int b = blockIdx.x;
    const int tid = threadIdx.x;
    const int lane = tid & 63;
    const int wv = tid >> 6;

    __shared__ float q_s[HDIM];
    __shared__ float we_s[HDIM];
    __shared__ float alpha[TPREM];
    __shared__ float red[4];

    for (int h = tid; h < HDIM; h += 256) {
        q_s[h] = q[(size_t)b * HDIM + h];
        we_s[h] = w_e[h];
    }
    __syncthreads();

    for (int t = wv; t < TPREM; t += 4) {
        const float* row = ws_hs + ((size_t)t * BATCH + b) * HDIM;
        float p = 0.f;
        for (int h = lane; h < HDIM; h += 64)
            p += we_s[h] * fast_tanh(row[h] + q_s[h]);
        #pragma unroll
        for (int off = 32; off; off >>= 1) p += __shfl_xor(p, off, 64);
        if (lane == 0) alpha[t] = p;
    }
    __syncthreads();

    if (wv < 2) {
        float ev = alpha[tid];
        float m = ev;
        #pragma unroll
        for (int off = 32; off; off >>= 1) m = fmaxf(m, __shfl_xor(m, off, 64));
        if (lane == 0) red[wv] = m;
        __syncthreads();
        float gm = fmaxf(red[0], red[1]);
        float e = __expf(ev - gm);
        alpha[tid] = e;
        float s = e;
        #pragma unroll
        for (int off = 32; off; off >>= 1) s += __shfl_xor(s, off, 64);
        if (lane == 0) red[2 + wv] = s;
        __syncthreads();
        alpha[tid] *= 1.f / (red[2] + red[3]);
    } else {
        __syncthreads();
        __syncthreads();
    }
    __syncthreads();

    for (int h = tid; h < HDIM; h += 256) {
        const float* hsb = h_s + (size_t)b * HDIM + h;
        float acc = 0.f;
        #pragma unroll 4
        for (int t = 0; t < TPREM; ++t)
            acc = fmaf(alpha[t], hsb[(size_t)t * BATCH * HDIM], acc);
        a_out[(size_t)b * HDIM + h] = acc;
    }
}

__global__ void k_fc(const float* __restrict__ h_m,
                     const float* __restrict__ fc_w,
                     const float* __restrict__ fc_b,
                     float* __restrict__ out)
{
    const int b = threadIdx.x;
    float a0 = 0.f, a1 = 0.f, a2 = 0.f;
    for (int h = 0; h < HDIM; ++h) {
        float v = h_m[(size_t)b * HDIM + h];
        a0 = fmaf(v, fc_w[h], a0);
        a1 = fmaf(v, fc_w[HDIM + h], a1);
        a2 = fmaf(v, fc_w[2 * HDIM + h], a2);
    }
    out[b * 3 + 0] = a0 + fc_b[0];
    out[b * 3 + 1] = a1 + fc_b[1];
    out[b * 3 + 2] = a2 + fc_b[2];
}

// ===========================================================================
extern "C" void kernel_launch(void* const* d_in, const int* in_sizes, int n_in,
                              void* d_out, int out_size, void* d_ws, size_t ws_size,
                              hipStream_t stream) {
    (void)in_sizes; (void)n_in; (void)out_size;
    const int*   premise    = (const int*)d_in[0];
    const int*   hypothesis = (const int*)d_in[2];
    const float* w2v        = (const float*)d_in[4];
    const float* w_e        = (const float*)d_in[5];
    const float* W_s        = (const float*)d_in[6];
    const float* W_t        = (const float*)d_in[7];
    const float* W_m        = (const float*)d_in[8];
    const float* fc_w       = (const float*)d_in[9];
    const float* fc_b       = (const float*)d_in[10];
    const float* pWih       = (const float*)d_in[11];
    const float* pWhh       = (const float*)d_in[12];
    const float* pbih       = (const float*)d_in[13];
    const float* pbhh       = (const float*)d_in[14];
    const float* hWih       = (const float*)d_in[15];
    const float* hWhh       = (const float*)d_in[16];
    const float* hbih       = (const float*)d_in[17];
    const float* hbhh       = (const float*)d_in[18];
    const float* mWih       = (const float*)d_in[19];
    const float* mbih       = (const float*)d_in[21];
    const float* mbhh       = (const float*)d_in[22];

    const size_t BH = (size_t)BATCH * HDIM;          // 76,800
    const size_t F32_CNT = (size_t)THYP * BH;        // 4,915,200
    const size_t NWHH = (size_t)38 * 1536 * 8;       // 466,944
    const size_t NWM3 = (size_t)75 * 1024 * 8;       // 614,400
    const size_t NWMT = (size_t)38 * 304 * 8;        // 92,416
    const size_t U16_CNT = 2 * (size_t)TPREM * BH
                         + (size_t)THYP * BH
                         + (size_t)TPREM * 64 * 1200 * 4
                         + (size_t)THYP * 64 * 1200 * 4
                         + 2 * NWHH + NWM3 + NWMT;
    const size_t NEED = F32_CNT * 4 + U16_CNT * 2 + 256;   // ~192 MB

    if (ws_size >= NEED) {
        Params p;
        p.premise = premise; p.hypothesis = hypothesis;
        p.w2v = w2v; p.w_e = w_e;
        p.W_s = W_s; p.W_t = W_t; p.W_m = W_m;
        p.fc_w = fc_w; p.fc_b = fc_b;
        p.pWih = pWih; p.pWhh = pWhh; p.pbih = pbih; p.pbhh = pbhh;
        p.hWih = hWih; p.hWhh = hWhh; p.hbih = hbih; p.hbhh = hbhh;
        p.mWih = mWih; p.mbih = mbih; p.mbhh = mbhh;

        float* f = (float*)d_ws;
        p.h_t_all = f; f += F32_CNT;
        unsigned short* u = (unsigned short*)f;
        p.hsT    = u; u += (size_t)TPREM * BH;
        p.wshsT  = u; u += (size_t)TPREM * BH;
        p.wthtB  = u; u += (size_t)THYP * BH;
        p.Xp     = u; u += (size_t)TPREM * 64 * 1200 * 4;
        p.Xh     = u; u += (size_t)THYP * 64 * 1200 * 4;
        p.WhhW_p = u; u += NWHH;
        p.WhhW_h = u; u += NWHH;
        p.WmW3   = u; u += NWM3;
        p.WmTw   = u;
        p.out = (float*)d_out;

        k_init<<<512, 256, 0, stream>>>(p);
        k_xproj<<<(256 + 128) * 19, 256, 0, stream>>>(p);
        match_b<<<256, 512, 0, stream>>>(p);
        k_proj<<<1536, 256, 0, stream>>>(p);
        match_d<<<BATCH, 1024, 0, stream>>>(p);
        return;
    }

    // ---- fallback: round-1 multi-kernel path ----
    float* ws    = (float*)d_ws;
    float* h_s   = ws;
    float* wshs  = h_s + (size_t)TPREM * BH;
    float* zeros = wshs + (size_t)TPREM * BH;
    float* c_p   = zeros + BH;
    float* c_h   = c_p + BH;
    float* c_m   = c_h + BH;
    float* ht0   = c_m + BH;
    float* ht1   = ht0 + BH;
    float* h_m   = ht1 + BH;
    float* qb    = h_m + BH;
    float* ab    = qb + BH;

    (void)hipMemsetAsync(zeros, 0, BH * sizeof(float), stream);
    (void)hipMemsetAsync(c_p,   0, BH * sizeof(float), stream);
    (void)hipMemsetAsync(c_h,   0, BH * sizeof(float), stream);
    (void)hipMemsetAsync(h_m,   0, BH * sizeof(float), stream);

    dim3 gGate(BATCH / 32, (HDIM + 15) / 16);

    for (int t = 0; t < TPREM; ++t) {
        const float* hp = t ? (h_s + (size_t)(t - 1) * BH) : zeros;
        k_lstm_gates<<<gGate, 256, 0, stream>>>(
            premise + (size_t)t * BATCH, w2v, nullptr, EDIM,
            hp, HDIM, pWih, EDIM, pWhh, HDIM,
            pbih, pbhh, c_p, c_p, h_s + (size_t)t * BH);
    }

    k_gemm_tn<64, 64, 4, 4, 16><<<dim3(TPREM * BATCH / 64, (HDIM + 63) / 64), 256, 0, stream>>>(
        h_s, HDIM, nullptr, 0, W_s, HDIM, nullptr, 0, wshs, TPREM * BATCH, HDIM);

    for (int k = 0; k < THYP; ++k) {
        const float* hp = k ? ((k & 1) ? ht0 : ht1) : zeros;
        float* hc = (k & 1) ? ht1 : ht0;
        k_lstm_gates<<<gGate, 256, 0, stream>>>(
            hypothesis + (size_t)k * BATCH, w2v, nullptr, EDIM,
            hp, HDIM, hWih, EDIM, hWhh, HDIM,
            hbih, hbhh, c_h, c_h, hc);
        k_gemm_tn<16, 64, 1, 4, 16><<<dim3(BATCH / 16, (HDIM + 63) / 64), 256, 0, stream>>>(
            hc, HDIM, h_m, HDIM, W_t, HDIM, W_m, HDIM, qb, BATCH, HDIM);
        k_attn<<<BATCH, 256, 0, stream>>>(wshs, h_s, qb, w_e, ab);
        k_lstm_gates<<<gGate, 256, 0, stream>>>(
            nullptr, nullptr, ab, HDIM,
            hc, HDIM, mWih, 2 * HDIM, mWih + HDIM, 2 * HDIM,
            mbih, mbhh, zeros, c_m, h_m);
    }

    k_fc<<<1, BATCH, 0, stream>>>(h_m, fc_w, fc_b, (float*)d_out);
}

// Round 17
// 4304.679 us; speedup vs baseline: 1.2033x; 1.2033x over previous
//
#include <hip/hip_runtime.h>
#include <hip/hip_bf16.h>
#include <cstddef>

// MatchLSTM round 17: compose proven winners only.
//  - match_b: R16's 256 blocks x 2 rows (proven -0.4 ms)
//  - match_d: R15's exact kernel (serial 304-thread q; VGPR-64 pipelined cell GEMV)
// Lesson encoded: any edit inside match_d perturbs regalloc and serializes the
// 5-deep loads (VGPR 64 -> <=52 is the canary). Do not touch match_d.
// V=50000, E=300, H=300, C=3, TP=128, TH=64, B=256
#define HDIM 300
#define EDIM 300
#define BATCH 256
#define TPREM 128
#define THYP 64
#define KTT 32

typedef unsigned short us8 __attribute__((ext_vector_type(8)));

__device__ __forceinline__ float fast_sigm(float x) {
    return 1.f / (1.f + __expf(-x));
}
__device__ __forceinline__ float fast_tanh(float x) {
    float e = __expf(2.f * x);
    return 1.f - 2.f / (e + 1.f);
}
__device__ __forceinline__ unsigned short f2bf(float f) {
    __hip_bfloat16 h = __float2bfloat16(f);
    return *reinterpret_cast<unsigned short*>(&h);
}
__device__ __forceinline__ float bf2f(unsigned short u) {
    return __uint_as_float((unsigned)u << 16);
}

struct Params {
    const int* premise; const int* hypothesis;
    const float* w2v; const float* w_e;
    const float* W_s; const float* W_t; const float* W_m;
    const float* fc_w; const float* fc_b;
    const float* pWih; const float* pWhh; const float* pbih; const float* pbhh;
    const float* hWih; const float* hWhh; const float* hbih; const float* hbhh;
    const float* mWih; const float* mbih; const float* mbhh;
    float* h_t_all;          // [TH][B][H] fp32
    unsigned short* hsT;     // [B][TP][H] bf16
    unsigned short* wshsT;   // [B][TP][H] bf16
    unsigned short* wthtB;   // [TH][B][H] bf16
    unsigned short* Xp;      // [TP][64][1200][4] bf16 (bias folded)
    unsigned short* Xh;      // [TH][64][1200][4] bf16
    unsigned short* WhhW_p;  // [38 kg][1536 c][8] bf16
    unsigned short* WhhW_h;
    unsigned short* WmW3;    // [75 kg][1024 c][8] bf16 (mWih i,g,o cols)
    unsigned short* WmTw;    // [38 kg][304 c][8] bf16 (W_m^T)
    float* out;
};

// ===========================================================================
// k_init: build wide transposed bf16 weight buffers. (R13 layouts)
// ===========================================================================
__global__ void k_init(Params p) {
    const int stride = gridDim.x * 256;
    const int i0 = blockIdx.x * 256 + threadIdx.x;
    for (int i = i0; i < 38 * 1536 * 8; i += stride) {
        int kg = i / (1536 * 8);
        int rem = i - kg * (1536 * 8);
        int c = rem >> 3, j = rem & 7;
        int k = 8 * kg + j;
        float vp = 0.f, vh = 0.f;
        if (c < 1200 && k < 300) {
            vp = p.pWhh[(size_t)c * 300 + k];
            vh = p.hWhh[(size_t)c * 300 + k];
        }
        p.WhhW_p[i] = f2bf(vp);
        p.WhhW_h[i] = f2bf(vh);
    }
    for (int i = i0; i < 75 * 1024 * 8; i += stride) {
        int kg = i / (1024 * 8);
        int rem = i - kg * (1024 * 8);
        int c = rem >> 3, j = rem & 7;
        int k = 8 * kg + j;
        float v = 0.f;
        if (c < 900 && k < 600) {
            int row = c + (c < 300 ? 0 : 300);
            v = p.mWih[(size_t)row * 600 + k];
        }
        p.WmW3[i] = f2bf(v);
    }
    for (int i = i0; i < 38 * 304 * 8; i += stride) {
        int kg = i / (304 * 8);
        int rem = i - kg * (304 * 8);
        int c = rem >> 3, j = rem & 7;
        int k = 8 * kg + j;
        p.WmTw[i] = f2bf((c < 300 && k < 300) ? p.W_m[(size_t)c * 300 + k] : 0.f);
    }
}

// ===========================================================================
// k_xproj: X = emb(tok) @ Wih^T + bih + bhh, bf16 [t][g][c][4].
// 128x64 tiles. Grid: (256 prem + 128 hyp) x 19.
// ===========================================================================
__global__ __launch_bounds__(256, 2) void k_xproj(Params p) {
    __shared__ __align__(16) float As[16][136];
    __shared__ __align__(16) float Bs[16][68];
    __shared__ int toks[128];

    const int bid = blockIdx.x;
    const int mt = bid / 19, nt = bid % 19;
    const bool isP = mt < 256;
    const int m0 = (isP ? mt : mt - 256) * 128;
    const int n0 = nt * 64;
    const int* tk = isP ? p.premise : p.hypothesis;
    const float* W = isP ? p.pWih : p.hWih;
    const float* b1 = isP ? p.pbih : p.hbih;
    const float* b2 = isP ? p.pbhh : p.hbhh;
    unsigned short* X = isP ? p.Xp : p.Xh;
    const int tid = threadIdx.x;

    if (tid < 128) toks[tid] = tk[m0 + tid];
    __syncthreads();

    const int tm = tid & 15, tn = tid >> 4;
    float acc[8][4] = {};
    for (int k0 = 0; k0 < 300; k0 += 16) {
        for (int i = tid; i < 2048; i += 256) {
            int kk = i & 15, ml = i >> 4;
            int k = k0 + kk;
            As[kk][ml] = (k < 300)
                ? p.w2v[(size_t)toks[ml] * 300 + k] : 0.f;
        }
        for (int i = tid; i < 1024; i += 256) {
            int kk = i & 15, nl = i >> 4;
            int c = n0 + nl, k = k0 + kk;
            Bs[kk][nl] = (c < 1200 && k < 300)
                ? W[(size_t)c * 300 + k] : 0.f;
        }
        __syncthreads();
        #pragma unroll
        for (int kk = 0; kk < 16; ++kk) {
            float a[8], w[4];
            #pragma unroll
            for (int i = 0; i < 8; ++i) a[i] = As[kk][tm * 8 + i];
            #pragma unroll
            for (int j = 0; j < 4; ++j) w[j] = Bs[kk][tn * 4 + j];
            #pragma unroll
            for (int i = 0; i < 8; ++i)
                #pragma unroll
                for (int j = 0; j < 4; ++j)
                    acc[i][j] = fmaf(a[i], w[j], acc[i][j]);
        }
        __syncthreads();
    }
    #pragma unroll
    for (int i = 0; i < 8; ++i) {
        int rr = m0 + tm * 8 + i;
        int t = rr >> 8, b = rr & 255;
        int g = b >> 2, r = b & 3;
        size_t base = (size_t)(t * 64 + g) * 1200;
        #pragma unroll
        for (int j = 0; j < 4; ++j) {
            int c = n0 + tn * 4 + j;
            if (c < 1200)
                X[(base + c) * 4 + r] = f2bf(acc[i][j] + b1[c] + b2[c]);
        }
    }
}

// ===========================================================================
// match_b: recurrences. Block = 2 rows, 256 blocks x 512 thr (R16 proven).
// ===========================================================================
__global__ __launch_bounds__(512, 2) void match_b(Params p) {
    __shared__ __align__(16) float2 A[304];    // h[t-1], 2 rows per float2
    __shared__ __align__(16) float2 G[1536];

    const int blk = blockIdx.x;
    const int tid = threadIdx.x;
    const bool isP = blk < 128;
    const int g = isP ? blk : blk - 128;
    const int b0 = g * 2;
    const int TS = isP ? TPREM : THYP;
    const unsigned short* WhhW = isP ? p.WhhW_p : p.WhhW_h;
    const unsigned short* Xbuf = isP ? p.Xp : p.Xh;
    const int g4 = b0 >> 2;          // 4-row group in X layout
    const int r0 = b0 & 3;           // 0 or 2

    if (tid < 304) A[tid] = {0, 0};
    float2 creg = {0, 0};
    __syncthreads();

    for (int t = 0; t < TS; ++t) {
        float2 ac0 = {0,0}, ac1 = {0,0}, ac2 = {0,0};
        {
            const unsigned short* w0 = WhhW + (size_t)tid * 8;
            const unsigned short* w1 = WhhW + (size_t)(tid + 512) * 8;
            const unsigned short* w2 = WhhW + (size_t)(tid + 1024) * 8;
            for (int kg = 0; kg < 38; kg += 2) {
                const size_t offA = (size_t)kg * (1536 * 8);
                const size_t offB = (size_t)(kg + 1) * (1536 * 8);
                us8 u0a = *reinterpret_cast<const us8*>(w0 + offA);
                us8 u1a = *reinterpret_cast<const us8*>(w1 + offA);
                us8 u2a = *reinterpret_cast<const us8*>(w2 + offA);
                us8 u0b = *reinterpret_cast<const us8*>(w0 + offB);
                us8 u1b = *reinterpret_cast<const us8*>(w1 + offB);
                us8 u2b = *reinterpret_cast<const us8*>(w2 + offB);
                #pragma unroll
                for (int j = 0; j < 8; ++j) {
                    float2 a = A[8 * kg + j];
                    float f0 = bf2f(u0a[j]), f1 = bf2f(u1a[j]), f2 = bf2f(u2a[j]);
                    ac0.x = fmaf(a.x, f0, ac0.x); ac0.y = fmaf(a.y, f0, ac0.y);
                    ac1.x = fmaf(a.x, f1, ac1.x); ac1.y = fmaf(a.y, f1, ac1.y);
                    ac2.x = fmaf(a.x, f2, ac2.x); ac2.y = fmaf(a.y, f2, ac2.y);
                }
                #pragma unroll
                for (int j = 0; j < 8; ++j) {
                    float2 a = A[8 * (kg + 1) + j];
                    float f0 = bf2f(u0b[j]), f1 = bf2f(u1b[j]), f2 = bf2f(u2b[j]);
                    ac0.x = fmaf(a.x, f0, ac0.x); ac0.y = fmaf(a.y, f0, ac0.y);
                    ac1.x = fmaf(a.x, f1, ac1.x); ac1.y = fmaf(a.y, f1, ac1.y);
                    ac2.x = fmaf(a.x, f2, ac2.x); ac2.y = fmaf(a.y, f2, ac2.y);
                }
            }
        }
        G[tid] = ac0;
        G[tid + 512] = ac1;
        G[tid + 1024] = ac2;
        __syncthreads();

        if (tid < 300) {
            const unsigned short* xb = Xbuf + (size_t)(t * 64 + g4) * 1200 * 4 + r0;
            ushort2 xi = *reinterpret_cast<const ushort2*>(xb + (size_t)tid * 4);
            ushort2 xf = *reinterpret_cast<const ushort2*>(xb + (size_t)(tid + 300) * 4);
            ushort2 xg = *reinterpret_cast<const ushort2*>(xb + (size_t)(tid + 600) * 4);
            ushort2 xo = *reinterpret_cast<const ushort2*>(xb + (size_t)(tid + 900) * 4);
            float2 g_i = G[tid], g_f = G[300 + tid];
            float2 g_g = G[600 + tid], g_o = G[900 + tid];
            float2 h2;
            {
                float gi = fast_sigm(g_i.x + bf2f(xi.x));
                float gf = fast_sigm(g_f.x + bf2f(xf.x));
                float gg = fast_tanh(g_g.x + bf2f(xg.x));
                float go = fast_sigm(g_o.x + bf2f(xo.x));
                creg.x = gf * creg.x + gi * gg; h2.x = go * fast_tanh(creg.x);
            }
            {
                float gi = fast_sigm(g_i.y + bf2f(xi.y));
                float gf = fast_sigm(g_f.y + bf2f(xf.y));
                float gg = fast_tanh(g_g.y + bf2f(xg.y));
                float go = fast_sigm(g_o.y + bf2f(xo.y));
                creg.y = gf * creg.y + gi * gg; h2.y = go * fast_tanh(creg.y);
            }
            A[tid] = h2;
            if (isP) {
                p.hsT[((size_t)(b0 + 0) * TPREM + t) * HDIM + tid] = f2bf(h2.x);
                p.hsT[((size_t)(b0 + 1) * TPREM + t) * HDIM + tid] = f2bf(h2.y);
            } else {
                const size_t rb = (size_t)(t * BATCH + b0);
                p.h_t_all[(rb + 0) * HDIM + tid] = h2.x;
                p.h_t_all[(rb + 1) * HDIM + tid] = h2.y;
            }
        }
        __syncthreads();
    }
}

// ===========================================================================
// k_proj: wshsT (premise, jobs 0..1023) and wthtB (hyp, 1024..1535).
// ===========================================================================
__global__ __launch_bounds__(256, 2) void k_proj(Params p) {
    __shared__ __align__(16) float hA[320][34];
    __shared__ __align__(16) float Bs[KTT][68];

    const int jb = blockIdx.x;
    const int tid = threadIdx.x;
    const int pb = tid & 15, hl = tid >> 4;
    const bool isP = jb < 1024;
    const int rt = isP ? jb : jb - 1024;
    const float* Wp = isP ? p.W_s : p.W_t;
    const int fb_c = tid >> 2, fb_k0 = (tid & 3) * 8;

    for (int i2 = tid; i2 < 32 * HDIM; i2 += 256) {
        int r = i2 / HDIM, k = i2 - r * HDIM;
        hA[k][r] = isP
            ? bf2f(p.hsT[(size_t)(rt * 32 + r) * HDIM + k])
            : p.h_t_all[(size_t)(rt * 32 + r) * HDIM + k];
    }
    for (int i2 = tid; i2 < 20 * 34; i2 += 256)
        hA[300 + i2 / 34][i2 % 34] = 0.f;
    __syncthreads();

    unsigned short* dst = isP ? p.wshsT : p.wthtB;

    for (int n0 = 0; n0 < HDIM; n0 += 64) {
        const int wrow = n0 + fb_c;
        const bool wvalid = wrow < HDIM;
        float acc[2][4] = {};
        for (int kc = 0; kc < HDIM; kc += KTT) {
            #pragma unroll
            for (int u = 0; u < 8; ++u) {
                int kk = fb_k0 + u, k = kc + kk;
                Bs[kk][fb_c] = (wvalid && k < HDIM)
                    ? Wp[(size_t)wrow * HDIM + k] : 0.f;
            }
            __syncthreads();
            #pragma unroll
            for (int kk = 0; kk < KTT; ++kk) {
                float2 av = *(const float2*)&hA[kc + kk][pb * 2];
                float4 wv = *(const float4*)&Bs[kk][hl * 4];
                acc[0][0] = fmaf(av.x, wv.x, acc[0][0]);
                acc[0][1] = fmaf(av.x, wv.y, acc[0][1]);
                acc[0][2] = fmaf(av.x, wv.z, acc[0][2]);
                acc[0][3] = fmaf(av.x, wv.w, acc[0][3]);
                acc[1][0] = fmaf(av.y, wv.x, acc[1][0]);
                acc[1][1] = fmaf(av.y, wv.y, acc[1][1]);
                acc[1][2] = fmaf(av.y, wv.z, acc[1][2]);
                acc[1][3] = fmaf(av.y, wv.w, acc[1][3]);
            }
            __syncthreads();
        }
        const int col = n0 + hl * 4;
        if (col < HDIM) {
            #pragma unroll
            for (int u = 0; u < 2; ++u) {
                size_t rr = (size_t)(rt * 32 + pb * 2 + u);
                ushort4 v4;
                v4.x = f2bf(acc[u][0]); v4.y = f2bf(acc[u][1]);
                v4.z = f2bf(acc[u][2]); v4.w = f2bf(acc[u][3]);
                *reinterpret_cast<ushort4*>(&dst[rr * HDIM + col]) = v4;
            }
        }
        __syncthreads();
    }
}

// ===========================================================================
// match_d: 256 blocks x 1024 thr, ONE row per block. (R15 EXACT — do not edit)
// ===========================================================================
__global__ __launch_bounds__(1024, 1) void match_d(Params p) {
    __shared__ __align__(16) float hm[304];
    __shared__ __align__(16) float q[304];
    __shared__ __align__(16) float we[304];
    __shared__ float alpha[TPREM];
    __shared__ __align__(16) float A6[608];
    __shared__ float G[1024];
    __shared__ __align__(16) float pvp[16][304];

    const int b = blockIdx.x;
    const int tid = threadIdx.x;
    const int lane = tid & 63;
    const int wv = tid >> 6;          // 0..15
    const unsigned short* wsb = p.wshsT + (size_t)b * TPREM * HDIM;
    const unsigned short* hsb = p.hsT + (size_t)b * TPREM * HDIM;

    float bi0 = 0.f, bi2 = 0.f, bi3 = 0.f;
    if (tid < 304) { hm[tid] = 0.f; we[tid] = 0.f; q[tid] = 0.f; }
    if (tid >= 600 && tid < 608) A6[tid] = 0.f;
    if (tid < 300) {
        we[tid] = p.w_e[tid];
        bi0 = p.mbih[tid] + p.mbhh[tid];
        bi2 = p.mbih[600 + tid] + p.mbhh[600 + tid];
        bi3 = p.mbih[900 + tid] + p.mbhh[900 + tid];
    }
    __syncthreads();

    for (int k = 0; k < THYP; ++k) {
        // q = W_m @ h_m + wt_ht (2-deep named, R13)
        if (tid < 304) {
            float acc = 0.f;
            const unsigned short* w0 = p.WmTw + (size_t)tid * 8;
            for (int kg = 0; kg < 38; kg += 2) {
                us8 ua = *reinterpret_cast<const us8*>(w0 + (size_t)kg * (304 * 8));
                us8 ub = *reinterpret_cast<const us8*>(w0 + (size_t)(kg + 1) * (304 * 8));
                #pragma unroll
                for (int j = 0; j < 8; ++j)
                    acc = fmaf(hm[8 * kg + j], bf2f(ua[j]), acc);
                #pragma unroll
                for (int j = 0; j < 8; ++j)
                    acc = fmaf(hm[8 * (kg + 1) + j], bf2f(ub[j]), acc);
            }
            if (tid < 300)
                q[tid] = acc + bf2f(p.wthtB[((size_t)k * BATCH + b) * HDIM + tid]);
        }
        __syncthreads();

        // e-pass (16 waves)
        for (int t = wv; t < TPREM; t += 16) {
            const unsigned short* row = wsb + (size_t)t * HDIM;
            ushort4 v4 = *reinterpret_cast<const ushort4*>(&row[4 * lane]);
            float4 q4 = *reinterpret_cast<const float4*>(&q[4 * lane]);
            float4 we4 = *reinterpret_cast<const float4*>(&we[4 * lane]);
            float pp;
            pp  = we4.x * fast_tanh(bf2f(v4.x) + q4.x);
            pp += we4.y * fast_tanh(bf2f(v4.y) + q4.y);
            pp += we4.z * fast_tanh(bf2f(v4.z) + q4.z);
            pp += we4.w * fast_tanh(bf2f(v4.w) + q4.w);
            if (lane < 44) {
                int h = 256 + lane;
                pp += we[h] * fast_tanh(bf2f(row[h]) + q[h]);
            }
            #pragma unroll
            for (int off = 32; off; off >>= 1) pp += __shfl_xor(pp, off, 64);
            if (lane == 0) alpha[t] = pp;
        }
        __syncthreads();

        // softmax over 128 (wave 0)
        if (wv == 0) {
            float e0 = alpha[lane], e1 = alpha[64 + lane];
            float m = fmaxf(e0, e1);
            #pragma unroll
            for (int off = 32; off; off >>= 1) m = fmaxf(m, __shfl_xor(m, off, 64));
            e0 = __expf(e0 - m); e1 = __expf(e1 - m);
            float s = e0 + e1;
            #pragma unroll
            for (int off = 32; off; off >>= 1) s += __shfl_xor(s, off, 64);
            float inv = 1.f / s;
            alpha[lane] = e0 * inv;
            alpha[64 + lane] = e1 * inv;
        }
        __syncthreads();

        // PV (16 waves)
        {
            float4 acc = {0, 0, 0, 0};
            float at = 0.f;
            for (int t = wv; t < TPREM; t += 16) {
                float wgt = alpha[t];
                const unsigned short* row = hsb + (size_t)t * HDIM;
                ushort4 v4 = *reinterpret_cast<const ushort4*>(&row[4 * lane]);
                acc.x = fmaf(wgt, bf2f(v4.x), acc.x);
                acc.y = fmaf(wgt, bf2f(v4.y), acc.y);
                acc.z = fmaf(wgt, bf2f(v4.z), acc.z);
                acc.w = fmaf(wgt, bf2f(v4.w), acc.w);
                if (lane < 44) at = fmaf(wgt, bf2f(row[256 + lane]), at);
            }
            *reinterpret_cast<float4*>(&pvp[wv][4 * lane]) = acc;
            if (lane < 44) pvp[wv][256 + lane] = at;
        }
        __syncthreads();

        // A6 = [ab | h_t]
        if (tid < 300) {
            float s = 0.f;
            #pragma unroll
            for (int w16 = 0; w16 < 16; ++w16) s += pvp[w16][tid];
            A6[tid] = s;
            A6[300 + tid] = p.h_t_all[((size_t)k * BATCH + b) * HDIM + tid];
        }
        __syncthreads();

        // cell GEMM: ONE col per thread; loads 5-deep NAMED (75 = 15*5, R13)
        {
            float acc0 = 0.f;
            const unsigned short* w0 = p.WmW3 + (size_t)tid * 8;
            for (int kb = 0; kb < 75; kb += 5) {
                us8 u0 = *reinterpret_cast<const us8*>(w0 + (size_t)(kb + 0) * (1024 * 8));
                us8 u1 = *reinterpret_cast<const us8*>(w0 + (size_t)(kb + 1) * (1024 * 8));
                us8 u2 = *reinterpret_cast<const us8*>(w0 + (size_t)(kb + 2) * (1024 * 8));
                us8 u3 = *reinterpret_cast<const us8*>(w0 + (size_t)(kb + 3) * (1024 * 8));
                us8 u4 = *reinterpret_cast<const us8*>(w0 + (size_t)(kb + 4) * (1024 * 8));
                #pragma unroll
                for (int j = 0; j < 8; ++j)
                    acc0 = fmaf(A6[8 * (kb + 0) + j], bf2f(u0[j]), acc0);
                #pragma unroll
                for (int j = 0; j < 8; ++j)
                    acc0 = fmaf(A6[8 * (kb + 1) + j], bf2f(u1[j]), acc0);
                #pragma unroll
                for (int j = 0; j < 8; ++j)
                    acc0 = fmaf(A6[8 * (kb + 2) + j], bf2f(u2[j]), acc0);
                #pragma unroll
                for (int j = 0; j < 8; ++j)
                    acc0 = fmaf(A6[8 * (kb + 3) + j], bf2f(u3[j]), acc0);
                #pragma unroll
                for (int j = 0; j < 8; ++j)
                    acc0 = fmaf(A6[8 * (kb + 4) + j], bf2f(u4[j]), acc0);
            }
            G[tid] = acc0;
        }
        __syncthreads();

        if (tid < 300) {
            float gi = fast_sigm(G[tid] + bi0);
            float gg = fast_tanh(G[300 + tid] + bi2);
            float go = fast_sigm(G[600 + tid] + bi3);
            hm[tid] = go * fast_tanh(gi * gg);
        }
        __syncthreads();
    }

    // FC (wave 0)
    if (wv == 0) {
        float p0 = 0.f, p1 = 0.f, p2 = 0.f;
        #pragma unroll
        for (int i = 0; i < 5; ++i) {
            int h = lane + 64 * i;
            if (h < HDIM) {
                float v = hm[h];
                p0 = fmaf(v, p.fc_w[h], p0);
                p1 = fmaf(v, p.fc_w[HDIM + h], p1);
                p2 = fmaf(v, p.fc_w[2 * HDIM + h], p2);
            }
        }
        #pragma unroll
        for (int off = 32; off; off >>= 1) {
            p0 += __shfl_xor(p0, off, 64);
            p1 += __shfl_xor(p1, off, 64);
            p2 += __shfl_xor(p2, off, 64);
        }
        if (lane == 0) {
            p.out[b * 3 + 0] = p0 + p.fc_b[0];
            p.out[b * 3 + 1] = p1 + p.fc_b[1];
            p.out[b * 3 + 2] = p2 + p.fc_b[2];
        }
    }
}

// ===========================================================================
// Fallback path: round-1 multi-kernel implementation (proven correct).
// ===========================================================================
__global__ void k_lstm_gates(
    const int* __restrict__ tok, const float* __restrict__ w2v,
    const float* __restrict__ A0, int K0,
    const float* __restrict__ A1, int K1,
    const float* __restrict__ W0, int ld0,
    const float* __restrict__ W1, int ld1,
    const float* __restrict__ bih, const float* __restrict__ bhh,
    const float* __restrict__ c_in, float* __restrict__ c_out,
    float* __restrict__ h_out)
{
    constexpr int KT = 32;
    __shared__ __align__(16) float As[KT][34];
    __shared__ __align__(16) float Bs[KT][68];

    const int tid = threadIdx.x;
    const int b0 = blockIdx.x * 32;
    const int hh0 = blockIdx.y * 16;
    const int K = K0 + K1;
    const int pb = tid & 15;
    const int hl = tid >> 4;
    const int fa_b = tid >> 3;
    const int fa_k0 = (tid & 7) * 4;
    const int fb_c = tid >> 2;
    const int fb_k0 = (tid & 3) * 8;
    const int fb_hh = hh0 + (fb_c >> 2);
    const int fb_g = fb_c & 3;
    const int fb_row = fb_g * HDIM + fb_hh;
    const bool fb_valid = fb_hh < HDIM;
    const int ga = b0 + fa_b;
    const int tok_b = tok ? tok[ga] : 0;

    float acc[2][4] = {{0.f,0.f,0.f,0.f},{0.f,0.f,0.f,0.f}};

    for (int k0 = 0; k0 < K; k0 += KT) {
        #pragma unroll
        for (int u = 0; u < 4; ++u) {
            int kk = fa_k0 + u;
            int k = k0 + kk;
            float v = 0.f;
            if (k < K0)      v = tok ? w2v[(size_t)tok_b * K0 + k]
                                     : A0[(size_t)ga * K0 + k];
            else if (k < K)  v = A1[(size_t)ga * K1 + (k - K0)];
            As[kk][fa_b] = v;
        }
        #pragma unroll
        for (int u = 0; u < 8; ++u) {
            int kk = fb_k0 + u;
            int k = k0 + kk;
            float v = 0.f;
            if (fb_valid) {
                if (k < K0)     v = W0[(size_t)fb_row * ld0 + k];
                else if (k < K) v = W1[(size_t)fb_row * ld1 + (k - K0)];
            }
            Bs[kk][fb_c] = v;
        }
        __syncthreads();
        #pragma unroll
        for (int kk = 0; kk < KT; ++kk) {
            float2 av = *(const float2*)&As[kk][pb * 2];
            float4 wv = *(const float4*)&Bs[kk][hl * 4];
            acc[0][0] = fmaf(av.x, wv.x, acc[0][0]);
            acc[0][1] = fmaf(av.x, wv.y, acc[0][1]);
            acc[0][2] = fmaf(av.x, wv.z, acc[0][2]);
            acc[0][3] = fmaf(av.x, wv.w, acc[0][3]);
            acc[1][0] = fmaf(av.y, wv.x, acc[1][0]);
            acc[1][1] = fmaf(av.y, wv.y, acc[1][1]);
            acc[1][2] = fmaf(av.y, wv.z, acc[1][2]);
            acc[1][3] = fmaf(av.y, wv.w, acc[1][3]);
        }
        __syncthreads();
    }

    const int hh = hh0 + hl;
    if (hh < HDIM) {
        float bi = bih[hh] + bhh[hh];
        float bf = bih[HDIM + hh] + bhh[HDIM + hh];
        float bg = bih[2 * HDIM + hh] + bhh[2 * HDIM + hh];
        float bo = bih[3 * HDIM + hh] + bhh[3 * HDIM + hh];
        #pragma unroll
        for (int u = 0; u < 2; ++u) {
            int b = b0 + pb * 2 + u;
            float gi = fast_sigm(acc[u][0] + bi);
            float gf = fast_sigm(acc[u][1] + bf);
            float gg = fast_tanh(acc[u][2] + bg);
            float go = fast_sigm(acc[u][3] + bo);
            float c = gf * c_in[(size_t)b * HDIM + hh] + gi * gg;
            c_out[(size_t)b * HDIM + hh] = c;
            h_out[(size_t)b * HDIM + hh] = go * fast_tanh(c);
        }
    }
}

template<int BM, int BN, int TM, int TN, int KT>
__global__ void k_gemm_tn(
    const float* __restrict__ A0, int K0,
    const float* __restrict__ A1, int K1,
    const float* __restrict__ B0, int ldb0,
    const float* __restrict__ B1, int ldb1,
    float* __restrict__ C, int M, int N)
{
    __shared__ __align__(16) float As[KT][BM + 4];
    __shared__ __align__(16) float Bs[KT][BN + 4];
    const int tid = threadIdx.x;
    const int m0 = blockIdx.x * BM;
    const int n0 = blockIdx.y * BN;
    const int K = K0 + K1;
    constexpr int TPM = BM / TM;
    const int tm = tid % TPM;
    const int tn = tid / TPM;

    float acc[TM][TN];
    #pragma unroll
    for (int i = 0; i < TM; ++i)
        #pragma unroll
        for (int j = 0; j < TN; ++j) acc[i][j] = 0.f;

    for (int k0 = 0; k0 < K; k0 += KT) {
        for (int i = tid; i < KT * BM; i += 256) {
            int kk = i % KT, ml = i / KT;
            int m = m0 + ml, k = k0 + kk;
            float v = 0.f;
            if (m < M) {
                if (k < K0)     v = A0[(size_t)m * K0 + k];
                else if (k < K) v = A1[(size_t)m * K1 + (k - K0)];
            }
            As[kk][ml] = v;
        }
        for (int i = tid; i < KT * BN; i += 256) {
            int kk = i % KT, nl = i / KT;
            int n = n0 + nl, k = k0 + kk;
            float v = 0.f;
            if (n < N) {
                if (k < K0)     v = B0[(size_t)n * ldb0 + k];
                else if (k < K) v = B1[(size_t)n * ldb1 + (k - K0)];
            }
            Bs[kk][nl] = v;
        }
        __syncthreads();
        #pragma unroll
        for (int kk = 0; kk < KT; ++kk) {
            float a[TM], w[TN];
            #pragma unroll
            for (int i = 0; i < TM; ++i) a[i] = As[kk][tm * TM + i];
            #pragma unroll
            for (int j = 0; j < TN; ++j) w[j] = Bs[kk][tn * TN + j];
            #pragma unroll
            for (int i = 0; i < TM; ++i)
                #pragma unroll
                for (int j = 0; j < TN; ++j)
                    acc[i][j] = fmaf(a[i], w[j], acc[i][j]);
        }
        __syncthreads();
    }
    #pragma unroll
    for (int i = 0; i < TM; ++i) {
        int m = m0 + tm * TM + i;
        if (m >= M) continue;
        #pragma unroll
        for (int j = 0; j < TN; ++j) {
            int n = n0 + tn * TN + j;
            if (n < N) C[(size_t)m * N + n] = acc[i][j];
        }
    }
}

__global__ void k_attn(const float* __restrict__ ws_hs,
                       const float* __restrict__ h_s,
                       const float* __restrict__ q,
                       const float* __restrict__ w_e,
                       float* __restrict__ a_out)
{
    const int b = blockIdx.x;
    const int tid = threadIdx.x;
    const int lane = tid & 63;
    const int wv = tid >> 6;

    __shared__ float q_s[HDIM];
    __shared__ float we_s[HDIM];
    __shared__ float alpha[TPREM];
    __shared__ float red[4];

    for (int h = tid; h < HDIM; h += 256) {
        q_s[h] = q[(size_t)b * HDIM + h];
        we_s[h] = w_e[h];
    }
    __syncthreads();

    for (int t = wv; t < TPREM; t += 4) {
        const float* row = ws_hs + ((size_t)t * BATCH + b) * HDIM;
        float p = 0.f;
        for (int h = lane; h < HDIM; h += 64)
            p += we_s[h] * fast_tanh(row[h] + q_s[h]);
        #pragma unroll
        for (int off = 32; off; off >>= 1) p += __shfl_xor(p, off, 64);
        if (lane == 0) alpha[t] = p;
    }
    __syncthreads();

    if (wv < 2) {
        float ev = alpha[tid];
        float m = ev;
        #pragma unroll
        for (int off = 32; off; off >>= 1) m = fmaxf(m, __shfl_xor(m, off, 64));
        if (lane == 0) red[wv] = m;
        __syncthreads();
        float gm = fmaxf(red[0], red[1]);
        float e = __expf(ev - gm);
        alpha[tid] = e;
        float s = e;
        #pragma unroll
        for (int off = 32; off; off >>= 1) s += __shfl_xor(s, off, 64);
        if (lane == 0) red[2 + wv] = s;
        __syncthreads();
        alpha[tid] *= 1.f / (red[2] + red[3]);
    } else {
        __syncthreads();
        __syncthreads();
    }
    __syncthreads();

    for (int h = tid; h < HDIM; h += 256) {
        const float* hsb = h_s + (size_t)b * HDIM + h;
        float acc = 0.f;
        #pragma unroll 4
        for (int t = 0; t < TPREM; ++t)
            acc = fmaf(alpha[t], hsb[(size_t)t * BATCH * HDIM], acc);
        a_out[(size_t)b * HDIM + h] = acc;
    }
}

__global__ void k_fc(const float* __restrict__ h_m,
                     const float* __restrict__ fc_w,
                     const float* __restrict__ fc_b,
                     float* __restrict__ out)
{
    const int b = threadIdx.x;
    float a0 = 0.f, a1 = 0.f, a2 = 0.f;
    for (int h = 0; h < HDIM; ++h) {
        float v = h_m[(size_t)b * HDIM + h];
        a0 = fmaf(v, fc_w[h], a0);
        a1 = fmaf(v, fc_w[HDIM + h], a1);
        a2 = fmaf(v, fc_w[2 * HDIM + h], a2);
    }
    out[b * 3 + 0] = a0 + fc_b[0];
    out[b * 3 + 1] = a1 + fc_b[1];
    out[b * 3 + 2] = a2 + fc_b[2];
}

// ===========================================================================
extern "C" void kernel_launch(void* const* d_in, const int* in_sizes, int n_in,
                              void* d_out, int out_size, void* d_ws, size_t ws_size,
                              hipStream_t stream) {
    (void)in_sizes; (void)n_in; (void)out_size;
    const int*   premise    = (const int*)d_in[0];
    const int*   hypothesis = (const int*)d_in[2];
    const float* w2v        = (const float*)d_in[4];
    const float* w_e        = (const float*)d_in[5];
    const float* W_s        = (const float*)d_in[6];
    const float* W_t        = (const float*)d_in[7];
    const float* W_m        = (const float*)d_in[8];
    const float* fc_w       = (const float*)d_in[9];
    const float* fc_b       = (const float*)d_in[10];
    const float* pWih       = (const float*)d_in[11];
    const float* pWhh       = (const float*)d_in[12];
    const float* pbih       = (const float*)d_in[13];
    const float* pbhh       = (const float*)d_in[14];
    const float* hWih       = (const float*)d_in[15];
    const float* hWhh       = (const float*)d_in[16];
    const float* hbih       = (const float*)d_in[17];
    const float* hbhh       = (const float*)d_in[18];
    const float* mWih       = (const float*)d_in[19];
    const float* mbih       = (const float*)d_in[21];
    const float* mbhh       = (const float*)d_in[22];

    const size_t BH = (size_t)BATCH * HDIM;          // 76,800
    const size_t F32_CNT = (size_t)THYP * BH;        // 4,915,200
    const size_t NWHH = (size_t)38 * 1536 * 8;       // 466,944
    const size_t NWM3 = (size_t)75 * 1024 * 8;       // 614,400
    const size_t NWMT = (size_t)38 * 304 * 8;        // 92,416
    const size_t U16_CNT = 2 * (size_t)TPREM * BH
                         + (size_t)THYP * BH
                         + (size_t)TPREM * 64 * 1200 * 4
                         + (size_t)THYP * 64 * 1200 * 4
                         + 2 * NWHH + NWM3 + NWMT;
    const size_t NEED = F32_CNT * 4 + U16_CNT * 2 + 256;   // ~192 MB

    if (ws_size >= NEED) {
        Params p;
        p.premise = premise; p.hypothesis = hypothesis;
        p.w2v = w2v; p.w_e = w_e;
        p.W_s = W_s; p.W_t = W_t; p.W_m = W_m;
        p.fc_w = fc_w; p.fc_b = fc_b;
        p.pWih = pWih; p.pWhh = pWhh; p.pbih = pbih; p.pbhh = pbhh;
        p.hWih = hWih; p.hWhh = hWhh; p.hbih = hbih; p.hbhh = hbhh;
        p.mWih = mWih; p.mbih = mbih; p.mbhh = mbhh;

        float* f = (float*)d_ws;
        p.h_t_all = f; f += F32_CNT;
        unsigned short* u = (unsigned short*)f;
        p.hsT    = u; u += (size_t)TPREM * BH;
        p.wshsT  = u; u += (size_t)TPREM * BH;
        p.wthtB  = u; u += (size_t)THYP * BH;
        p.Xp     = u; u += (size_t)TPREM * 64 * 1200 * 4;
        p.Xh     = u; u += (size_t)THYP * 64 * 1200 * 4;
        p.WhhW_p = u; u += NWHH;
        p.WhhW_h = u; u += NWHH;
        p.WmW3   = u; u += NWM3;
        p.WmTw   = u;
        p.out = (float*)d_out;

        k_init<<<512, 256, 0, stream>>>(p);
        k_xproj<<<(256 + 128) * 19, 256, 0, stream>>>(p);
        match_b<<<256, 512, 0, stream>>>(p);
        k_proj<<<1536, 256, 0, stream>>>(p);
        match_d<<<BATCH, 1024, 0, stream>>>(p);
        return;
    }

    // ---- fallback: round-1 multi-kernel path ----
    float* ws    = (float*)d_ws;
    float* h_s   = ws;
    float* wshs  = h_s + (size_t)TPREM * BH;
    float* zeros = wshs + (size_t)TPREM * BH;
    float* c_p   = zeros + BH;
    float* c_h   = c_p + BH;
    float* c_m   = c_h + BH;
    float* ht0   = c_m + BH;
    float* ht1   = ht0 + BH;
    float* h_m   = ht1 + BH;
    float* qb    = h_m + BH;
    float* ab    = qb + BH;

    (void)hipMemsetAsync(zeros, 0, BH * sizeof(float), stream);
    (void)hipMemsetAsync(c_p,   0, BH * sizeof(float), stream);
    (void)hipMemsetAsync(c_h,   0, BH * sizeof(float), stream);
    (void)hipMemsetAsync(h_m,   0, BH * sizeof(float), stream);

    dim3 gGate(BATCH / 32, (HDIM + 15) / 16);

    for (int t = 0; t < TPREM; ++t) {
        const float* hp = t ? (h_s + (size_t)(t - 1) * BH) : zeros;
        k_lstm_gates<<<gGate, 256, 0, stream>>>(
            premise + (size_t)t * BATCH, w2v, nullptr, EDIM,
            hp, HDIM, pWih, EDIM, pWhh, HDIM,
            pbih, pbhh, c_p, c_p, h_s + (size_t)t * BH);
    }

    k_gemm_tn<64, 64, 4, 4, 16><<<dim3(TPREM * BATCH / 64, (HDIM + 63) / 64), 256, 0, stream>>>(
        h_s, HDIM, nullptr, 0, W_s, HDIM, nullptr, 0, wshs, TPREM * BATCH, HDIM);

    for (int k = 0; k < THYP; ++k) {
        const float* hp = k ? ((k & 1) ? ht0 : ht1) : zeros;
        float* hc = (k & 1) ? ht1 : ht0;
        k_lstm_gates<<<gGate, 256, 0, stream>>>(
            hypothesis + (size_t)k * BATCH, w2v, nullptr, EDIM,
            hp, HDIM, hWih, EDIM, hWhh, HDIM,
            hbih, hbhh, c_h, c_h, hc);
        k_gemm_tn<16, 64, 1, 4, 16><<<dim3(BATCH / 16, (HDIM + 63) / 64), 256, 0, stream>>>(
            hc, HDIM, h_m, HDIM, W_t, HDIM, W_m, HDIM, qb, BATCH, HDIM);
        k_attn<<<BATCH, 256, 0, stream>>>(wshs, h_s, qb, w_e, ab);
        k_lstm_gates<<<gGate, 256, 0, stream>>>(
            nullptr, nullptr, ab, HDIM,
            hc, HDIM, mWih, 2 * HDIM, mWih + HDIM, 2 * HDIM,
            mbih, mbhh, zeros, c_m, h_m);
    }

    k_fc<<<1, BATCH, 0, stream>>>(h_m, fc_w, fc_b, (float*)d_out);
}